// Round 3
// baseline (251.026 us; speedup 1.0000x reference)
//
#include <hip/hip_runtime.h>
#include <hip/hip_bf16.h>
#include <math.h>

// Problem constants
#define BB    128
#define TT    32
#define DD    1024
#define NADA  1024
#define NINT  1024
#define NRANK 8
#define LNEPS 1e-5f
#define SPLITS 8
#define TKCH  8   // tmat k-chunks

using bf16x8 = __attribute__((ext_vector_type(8))) short;
using f32x4  = __attribute__((ext_vector_type(4))) float;

__device__ __forceinline__ short f2bf(float f) {
    __hip_bfloat16 h = __float2bfloat16(f);  // RNE
    return *reinterpret_cast<short*>(&h);
}

__device__ __forceinline__ void async16(const void* g, void* l) {
    __builtin_amdgcn_global_load_lds(
        (const __attribute__((address_space(1))) void*)g,
        (__attribute__((address_space(3))) void*)l, 16, 0, 0);
}

// ---------------------------------------------------------------------------
// LayerNorm over ada_emb rows -> bf16 output
// ---------------------------------------------------------------------------
__global__ __launch_bounds__(256) void ln_kernel(
    const float* __restrict__ ada, const float* __restrict__ g,
    const float* __restrict__ beta, short* __restrict__ ae)
{
    const int b = blockIdx.x;
    const float* row = ada + (size_t)b * NADA;
    float sum = 0.f, sumsq = 0.f;
    for (int i = threadIdx.x; i < NADA; i += 256) {
        float v = row[i];
        sum += v; sumsq += v * v;
    }
    #pragma unroll
    for (int off = 32; off > 0; off >>= 1) {
        sum   += __shfl_down(sum, off);
        sumsq += __shfl_down(sumsq, off);
    }
    __shared__ float s1[4], s2[4];
    const int wid = threadIdx.x >> 6, lane = threadIdx.x & 63;
    if (lane == 0) { s1[wid] = sum; s2[wid] = sumsq; }
    __syncthreads();
    if (threadIdx.x == 0) {
        float a = 0.f, c = 0.f;
        for (int i = 0; i < 4; ++i) { a += s1[i]; c += s2[i]; }
        s1[0] = a; s2[0] = c;
    }
    __syncthreads();
    const float mu  = s1[0] * (1.f / NADA);
    const float var = s2[0] * (1.f / NADA) - mu * mu;
    const float inv = rsqrtf(var + LNEPS);
    for (int i = threadIdx.x; i < NADA; i += 256) {
        ae[(size_t)b * NADA + i] = f2bf((row[i] - mu) * inv * g[i] + beta[i]);
    }
}

// ---------------------------------------------------------------------------
// Flat fp32 -> bf16 cast (x)
// ---------------------------------------------------------------------------
__global__ __launch_bounds__(256) void cast_kernel(
    const float* __restrict__ in, short* __restrict__ out)
{
    const int idx = blockIdx.x * 256 + threadIdx.x;
    float4 v = reinterpret_cast<const float4*>(in)[idx];
    short4 p;
    p.x = f2bf(v.x); p.y = f2bf(v.y); p.z = f2bf(v.z); p.w = f2bf(v.w);
    reinterpret_cast<short4*>(out)[idx] = p;
}

// ---------------------------------------------------------------------------
// Transpose + cast: in (K,N) fp32 row-major -> out (N,K) bf16 row-major
// 64x64 tiles through LDS.
// ---------------------------------------------------------------------------
__global__ __launch_bounds__(256) void tcast_kernel(
    const float* __restrict__ in, short* __restrict__ out, int K, int N)
{
    __shared__ float t[64][68];
    const int n0 = blockIdx.x * 64, k0 = blockIdx.y * 64;
    const int tid = threadIdx.x;
    #pragma unroll
    for (int it = 0; it < 4; ++it) {
        const int idx = it * 256 + tid;
        const int r = idx >> 4, c4 = (idx & 15) * 4;
        float4 v = *(const float4*)(in + (size_t)(k0 + r) * N + n0 + c4);
        t[r][c4 + 0] = v.x; t[r][c4 + 1] = v.y;
        t[r][c4 + 2] = v.z; t[r][c4 + 3] = v.w;
    }
    __syncthreads();
    #pragma unroll
    for (int it = 0; it < 4; ++it) {
        const int idx = it * 256 + tid;
        const int rn = idx >> 4, c4 = (idx & 15) * 4;
        short4 p;
        p.x = f2bf(t[c4 + 0][rn]); p.y = f2bf(t[c4 + 1][rn]);
        p.z = f2bf(t[c4 + 2][rn]); p.w = f2bf(t[c4 + 3][rn]);
        *(short4*)(out + (size_t)(n0 + rn) * K + k0 + c4) = p;
    }
}

// ---------------------------------------------------------------------------
// m97-style bf16 MFMA GEMM. A (M,K) bf16 row-major, Bt (N,K) bf16 row-major.
// global_load_lds width-16 staging, ds_read_b128 fragments, 2x2 waves.
// EPI==0: partial to C[z][M][N] (split-K)
// EPI==1: C = acc + bias (fp32)
// EPI==2: C = acc + resid + rank-8 LoRA (fp32)
// ---------------------------------------------------------------------------
template <int BM, int BN, int EPI>
__global__ __launch_bounds__(256) void mgemm(
    const short* __restrict__ A, const short* __restrict__ Bt,
    const float* __restrict__ bias, float* __restrict__ C,
    int M, int N, int K, int kLen,
    const float* __restrict__ resid, const float* __restrict__ tmat,
    const float* __restrict__ xw)
{
    constexpr int LA = BM * 32 / (256 * 8);  // async16 instrs per thread (A)
    constexpr int LB = BN * 32 / (256 * 8);
    constexpr int MT = 4;                    // 16-row tiles per wave (BM/2/16)
    constexpr int NT = BN / 32;              // 16-col tiles per wave

    __shared__ __align__(16) short As[BM * 32];
    __shared__ __align__(16) short Bs[BN * 32];

    const int bm = blockIdx.y * BM;
    const int bn = blockIdx.x * BN;
    const int kStart = blockIdx.z * kLen;
    const int tid = threadIdx.x;
    const int wave = tid >> 6, lane = tid & 63;
    const int wm0 = (wave >> 1) * 64;
    const int wn0 = (wave & 1) * (BN / 2);
    const int quad = lane >> 4, r16 = lane & 15;

    f32x4 acc[MT][NT] = {};

    for (int kt = 0; kt < kLen; kt += 32) {
        const int k0 = kStart + kt;
        #pragma unroll
        for (int s = 0; s < LA; ++s) {
            const int c = s * 256 + tid;
            async16(A + (size_t)(bm + (c >> 2)) * K + k0 + (c & 3) * 8, &As[c * 8]);
        }
        #pragma unroll
        for (int s = 0; s < LB; ++s) {
            const int c = s * 256 + tid;
            async16(Bt + (size_t)(bn + (c >> 2)) * K + k0 + (c & 3) * 8, &Bs[c * 8]);
        }
        __syncthreads();
        bf16x8 af[MT], bfr[NT];
        #pragma unroll
        for (int i = 0; i < MT; ++i)
            af[i] = *reinterpret_cast<const bf16x8*>(&As[(wm0 + i * 16 + r16) * 32 + quad * 8]);
        #pragma unroll
        for (int j = 0; j < NT; ++j)
            bfr[j] = *reinterpret_cast<const bf16x8*>(&Bs[(wn0 + j * 16 + r16) * 32 + quad * 8]);
        #pragma unroll
        for (int i = 0; i < MT; ++i)
            #pragma unroll
            for (int j = 0; j < NT; ++j)
                acc[i][j] = __builtin_amdgcn_mfma_f32_16x16x32_bf16(
                    af[i], bfr[j], acc[i][j], 0, 0, 0);
        __syncthreads();
    }

    // D layout: col = lane&15, row = quad*4 + reg
    #pragma unroll
    for (int i = 0; i < MT; ++i) {
        #pragma unroll
        for (int r = 0; r < 4; ++r) {
            const int m = bm + wm0 + i * 16 + quad * 4 + r;
            float t8[NRANK];
            if (EPI == 2) {
                float4 t0 = *(const float4*)(tmat + (size_t)m * NRANK);
                float4 t1 = *(const float4*)(tmat + (size_t)m * NRANK + 4);
                t8[0] = t0.x; t8[1] = t0.y; t8[2] = t0.z; t8[3] = t0.w;
                t8[4] = t1.x; t8[5] = t1.y; t8[6] = t1.z; t8[7] = t1.w;
            }
            #pragma unroll
            for (int j = 0; j < NT; ++j) {
                const int n = bn + wn0 + j * 16 + r16;
                float v = acc[i][j][r];
                if (EPI == 0) {
                    C[((size_t)blockIdx.z * M + m) * N + n] = v;
                } else if (EPI == 1) {
                    C[(size_t)m * N + n] = v + bias[n];
                } else {
                    v += resid[(size_t)m * N + n];
                    const int b = m >> 5;
                    const float* xb = xw + (size_t)b * (2 * DD * NRANK) + DD * NRANK
                                         + (size_t)n * NRANK;
                    float4 x0 = *(const float4*)xb;
                    float4 x1 = *(const float4*)(xb + 4);
                    v += t8[0] * x0.x + t8[1] * x0.y + t8[2] * x0.z + t8[3] * x0.w
                       + t8[4] * x1.x + t8[5] * x1.y + t8[6] * x1.z + t8[7] * x1.w;
                    C[(size_t)m * N + n] = v;
                }
            }
        }
    }
}

// ---------------------------------------------------------------------------
// Combine split-K partials + bias + exact GELU -> h (bf16)
// ---------------------------------------------------------------------------
__global__ __launch_bounds__(256) void combine_gelu(
    const float* __restrict__ part, const float* __restrict__ b1,
    short* __restrict__ h)
{
    const int idx = blockIdx.x * 256 + threadIdx.x;  // < 128*1024
    float s = b1[idx & (NINT - 1)];
    #pragma unroll
    for (int z = 0; z < SPLITS; ++z) s += part[(size_t)z * BB * NINT + idx];
    s = 0.5f * s * (1.f + erff(s * 0.70710678118654752f));
    h[idx] = f2bf(s);
}

// ---------------------------------------------------------------------------
// tmat partials: tp[ch][b][m][r] = sum_{c in chunk} x[b,m,c] * x_a[b,c,r]
// grid (BB, TKCH); fp32 for accuracy.
// ---------------------------------------------------------------------------
__global__ __launch_bounds__(256) void tpart_kernel(
    const float* __restrict__ x, const float* __restrict__ xw,
    float* __restrict__ tp)
{
    __shared__ float xa[(DD / TKCH) * NRANK];  // 4 KB chunk [c][r]
    const int b = blockIdx.x, ch = blockIdx.y;
    const float* src = xw + (size_t)b * (2 * DD * NRANK) + (size_t)ch * (DD / TKCH) * NRANK;
    float4 v = *(const float4*)(src + threadIdx.x * 4);
    *(float4*)(xa + threadIdx.x * 4) = v;
    __syncthreads();
    const int m = threadIdx.x >> 3;
    const int r = threadIdx.x & 7;
    const float* xrow = x + ((size_t)b * TT + m) * DD + ch * (DD / TKCH);
    float accv = 0.f;
    #pragma unroll 4
    for (int c = 0; c < DD / TKCH; c += 4) {
        float4 xr = *(const float4*)(xrow + c);
        accv += xr.x * xa[(c + 0) * NRANK + r];
        accv += xr.y * xa[(c + 1) * NRANK + r];
        accv += xr.z * xa[(c + 2) * NRANK + r];
        accv += xr.w * xa[(c + 3) * NRANK + r];
    }
    tp[((size_t)ch * BB * TT + (size_t)b * TT + m) * NRANK + r] = accv;
}

__global__ __launch_bounds__(256) void tcomb_kernel(
    const float* __restrict__ tp, float* __restrict__ tm)
{
    const int i = blockIdx.x * 256 + threadIdx.x;  // < 128*32*8
    float s = 0.f;
    #pragma unroll
    for (int ch = 0; ch < TKCH; ++ch) s += tp[(size_t)ch * BB * TT * NRANK + i];
    tm[i] = s;
}

// ---------------------------------------------------------------------------
extern "C" void kernel_launch(void* const* d_in, const int* in_sizes, int n_in,
                              void* d_out, int out_size, void* d_ws, size_t ws_size,
                              hipStream_t stream)
{
    const float* x    = (const float*)d_in[0];  // (128,32,1024)
    const float* ada  = (const float*)d_in[1];  // (128,1024)
    const float* base = (const float*)d_in[2];  // (1024,1024)
    const float* w1   = (const float*)d_in[3];  // (1024,1024)
    const float* b1   = (const float*)d_in[4];  // (1024,)
    const float* w2   = (const float*)d_in[5];  // (1024,16384)
    const float* b2   = (const float*)d_in[6];  // (16384,)
    const float* lng  = (const float*)d_in[7];  // (1024,)
    const float* lnb  = (const float*)d_in[8];  // (1024,)
    float* out = (float*)d_out;

    char* w = (char*)d_ws;
    short* x_bf  = (short*)w;  w += (size_t)8 << 20;   // 4096x1024 bf16
    short* w2t   = (short*)w;  w += (size_t)32 << 20;  // 16384x1024 bf16
    short* w1t   = (short*)w;  w += (size_t)2 << 20;   // 1024x1024 bf16
    short* baset = (short*)w;  w += (size_t)2 << 20;   // 1024x1024 bf16
    short* ae_bf = (short*)w;  w += (size_t)256 << 10; // 128x1024 bf16
    short* h_bf  = (short*)w;  w += (size_t)256 << 10; // 128x1024 bf16
    float* xw    = (float*)w;  w += (size_t)8 << 20;   // 128x16384 fp32
    float* tm    = (float*)w;  w += (size_t)128 << 10; // 128x32x8 fp32
    float* part  = (float*)w;                          // 4 MB (aliases tp)
    float* tp    = part;

    // independent pre-casts
    cast_kernel<<<BB * TT * DD / 1024, 256, 0, stream>>>(x, x_bf);
    tcast_kernel<<<dim3(NINT / 64, NADA / 64), 256, 0, stream>>>(w1, w1t, NADA, NINT);
    tcast_kernel<<<dim3(DD / 64, DD / 64), 256, 0, stream>>>(base, baset, DD, DD);
    tcast_kernel<<<dim3(2 * DD * NRANK / 64, NINT / 64), 256, 0, stream>>>(w2, w2t, NINT, 2 * DD * NRANK);
    // 1. layernorm -> bf16
    ln_kernel<<<BB, 256, 0, stream>>>(ada, lng, lnb, ae_bf);
    // 2. ae@w1 split-K partials, then gelu(sum+b1) -> h_bf
    mgemm<128, 64, 0><<<dim3(NINT / 64, 1, SPLITS), 256, 0, stream>>>(
        ae_bf, w1t, nullptr, part, BB, NINT, NADA, NADA / SPLITS, nullptr, nullptr, nullptr);
    combine_gelu<<<BB * NINT / 256, 256, 0, stream>>>(part, b1, h_bf);
    // 3. xw = h@w2 + b2
    mgemm<128, 64, 1><<<dim3(2 * DD * NRANK / 64, 1, 1), 256, 0, stream>>>(
        h_bf, w2t, b2, xw, BB, 2 * DD * NRANK, NINT, NINT, nullptr, nullptr, nullptr);
    // 4. tmat = per-sample x@x_a (split over k, fp32)
    tpart_kernel<<<dim3(BB, TKCH), 256, 0, stream>>>(x, xw, tp);
    tcomb_kernel<<<BB * TT * NRANK / 256, 256, 0, stream>>>(tp, tm);
    // 5. out = x@base + x + t@x_b^T
    mgemm<128, 128, 2><<<dim3(DD / 128, BB * TT / 128, 1), 256, 0, stream>>>(
        x_bf, baset, nullptr, out, BB * TT, DD, DD, DD, x, tm, xw);
}

// Round 4
// 197.817 us; speedup vs baseline: 1.2690x; 1.2690x over previous
//
#include <hip/hip_runtime.h>
#include <hip/hip_bf16.h>
#include <math.h>

// Problem constants
#define BB    128
#define TT    32
#define DD    1024
#define NADA  1024
#define NINT  1024
#define NRANK 8
#define LNEPS 1e-5f
#define SPLITS 8
#define TKCH  8   // tmat k-chunks

using bf16x8 = __attribute__((ext_vector_type(8))) short;
using f32x4  = __attribute__((ext_vector_type(4))) float;

__device__ __forceinline__ short f2bf(float f) {
    __hip_bfloat16 h = __float2bfloat16(f);  // RNE
    return *reinterpret_cast<short*>(&h);
}

__device__ __forceinline__ void async16(const void* g, void* l) {
    __builtin_amdgcn_global_load_lds(
        (const __attribute__((address_space(1))) void*)g,
        (__attribute__((address_space(3))) void*)l, 16, 0, 0);
}

// ---------------------------------------------------------------------------
// LayerNorm over ada_emb rows -> bf16 output
// ---------------------------------------------------------------------------
__global__ __launch_bounds__(256) void ln_kernel(
    const float* __restrict__ ada, const float* __restrict__ g,
    const float* __restrict__ beta, short* __restrict__ ae)
{
    const int b = blockIdx.x;
    const float* row = ada + (size_t)b * NADA;
    float sum = 0.f, sumsq = 0.f;
    for (int i = threadIdx.x; i < NADA; i += 256) {
        float v = row[i];
        sum += v; sumsq += v * v;
    }
    #pragma unroll
    for (int off = 32; off > 0; off >>= 1) {
        sum   += __shfl_down(sum, off);
        sumsq += __shfl_down(sumsq, off);
    }
    __shared__ float s1[4], s2[4];
    const int wid = threadIdx.x >> 6, lane = threadIdx.x & 63;
    if (lane == 0) { s1[wid] = sum; s2[wid] = sumsq; }
    __syncthreads();
    if (threadIdx.x == 0) {
        float a = 0.f, c = 0.f;
        for (int i = 0; i < 4; ++i) { a += s1[i]; c += s2[i]; }
        s1[0] = a; s2[0] = c;
    }
    __syncthreads();
    const float mu  = s1[0] * (1.f / NADA);
    const float var = s2[0] * (1.f / NADA) - mu * mu;
    const float inv = rsqrtf(var + LNEPS);
    for (int i = threadIdx.x; i < NADA; i += 256) {
        ae[(size_t)b * NADA + i] = f2bf((row[i] - mu) * inv * g[i] + beta[i]);
    }
}

// ---------------------------------------------------------------------------
// Flat fp32 -> bf16 cast (x)
// ---------------------------------------------------------------------------
__global__ __launch_bounds__(256) void cast_kernel(
    const float* __restrict__ in, short* __restrict__ out)
{
    const int idx = blockIdx.x * 256 + threadIdx.x;
    float4 v = reinterpret_cast<const float4*>(in)[idx];
    short4 p;
    p.x = f2bf(v.x); p.y = f2bf(v.y); p.z = f2bf(v.z); p.w = f2bf(v.w);
    reinterpret_cast<short4*>(out)[idx] = p;
}

// ---------------------------------------------------------------------------
// Transpose + cast: in (K,N) fp32 row-major -> out (N,K) bf16 row-major.
// ADDI: add identity (folds the residual x into base @ x).
// ---------------------------------------------------------------------------
template <bool ADDI>
__global__ __launch_bounds__(256) void tcast_kernel(
    const float* __restrict__ in, short* __restrict__ out, int K, int N)
{
    __shared__ float t[64][68];
    const int n0 = blockIdx.x * 64, k0 = blockIdx.y * 64;
    const int tid = threadIdx.x;
    #pragma unroll
    for (int it = 0; it < 4; ++it) {
        const int idx = it * 256 + tid;
        const int r = idx >> 4, c4 = (idx & 15) * 4;
        float4 v = *(const float4*)(in + (size_t)(k0 + r) * N + n0 + c4);
        t[r][c4 + 0] = v.x; t[r][c4 + 1] = v.y;
        t[r][c4 + 2] = v.z; t[r][c4 + 3] = v.w;
    }
    __syncthreads();
    #pragma unroll
    for (int it = 0; it < 4; ++it) {
        const int idx = it * 256 + tid;
        const int rn = idx >> 4, c4 = (idx & 15) * 4;
        short4 p;
        float f0 = t[c4 + 0][rn], f1 = t[c4 + 1][rn];
        float f2 = t[c4 + 2][rn], f3 = t[c4 + 3][rn];
        if (ADDI) {
            const int n = n0 + rn;
            if (k0 + c4 + 0 == n) f0 += 1.f;
            if (k0 + c4 + 1 == n) f1 += 1.f;
            if (k0 + c4 + 2 == n) f2 += 1.f;
            if (k0 + c4 + 3 == n) f3 += 1.f;
        }
        p.x = f2bf(f0); p.y = f2bf(f1); p.z = f2bf(f2); p.w = f2bf(f3);
        *(short4*)(out + (size_t)(n0 + rn) * K + k0 + c4) = p;
    }
}

// ---------------------------------------------------------------------------
// bf16 MFMA GEMM. A (M,K) bf16 row-major, Bt (N,K) bf16 row-major.
// async global->LDS staging, ds_read_b128 fragments, WMxWN wave grid.
// EPI==0: partial to C[z][M][N] (split-K)
// EPI==1: C = acc + bias (fp32)
// EPI==2: C = acc + rank-8 LoRA from LDS-staged tmat/x_b (fp32)
// ---------------------------------------------------------------------------
template <int BM, int BN, int WM, int WN, int EPI>
__global__ __launch_bounds__(256, 2) void mgemm(
    const short* __restrict__ A, const short* __restrict__ Bt,
    const float* __restrict__ bias, float* __restrict__ C,
    int M, int N, int K, int kLen,
    const float* __restrict__ tmat, const float* __restrict__ xw)
{
    constexpr int MT = BM / WM / 16;
    constexpr int NT = BN / WN / 16;
    constexpr int LA = BM / 64;   // async16 per thread for A tile
    constexpr int LB = BN / 64;

    __shared__ __align__(16) short As[BM * 32];
    __shared__ __align__(16) short Bs[BN * 32];
    __shared__ float tmS[(EPI == 2) ? BM * 8 : 1];
    __shared__ float xbS[(EPI == 2) ? (BM / 32) * BN * 8 : 1];

    const int bm = blockIdx.y * BM;
    const int bn = blockIdx.x * BN;
    const int kStart = blockIdx.z * kLen;
    const int tid = threadIdx.x;
    const int wave = tid >> 6, lane = tid & 63;
    const int wm0 = (wave / WN) * (BM / WM);
    const int wn0 = (wave % WN) * (BN / WN);
    const int quad = lane >> 4, r16 = lane & 15;

    if constexpr (EPI == 2) {
        // stage tmat slice (BM x 8) and x_b slice ((BM/32) samples x BN x 8)
        const int b0 = bm >> 5;
        #pragma unroll
        for (int s = 0; s < BM * 8 / 1024; ++s) {
            const int i4 = s * 256 + tid;
            *(float4*)&tmS[i4 * 4] = *(const float4*)(tmat + (size_t)bm * 8 + i4 * 4);
        }
        const int grp = tid >> 6;     // sample within block (BM=128 -> 4)
        const int inner = tid & 63;   // BN*8 = 512 floats per sample, 8/lane
        const float* src = xw + (size_t)(b0 + grp) * (2 * DD * NRANK) + DD * NRANK
                              + (size_t)bn * 8;
        *(float4*)&xbS[grp * BN * 8 + inner * 8]     = *(const float4*)(src + inner * 8);
        *(float4*)&xbS[grp * BN * 8 + inner * 8 + 4] = *(const float4*)(src + inner * 8 + 4);
    }

    f32x4 acc[MT][NT] = {};

    for (int kt = 0; kt < kLen; kt += 32) {
        const int k0 = kStart + kt;
        #pragma unroll
        for (int s = 0; s < LA; ++s) {
            const int c = s * 256 + tid;
            async16(A + (size_t)(bm + (c >> 2)) * K + k0 + (c & 3) * 8, &As[c * 8]);
        }
        #pragma unroll
        for (int s = 0; s < LB; ++s) {
            const int c = s * 256 + tid;
            async16(Bt + (size_t)(bn + (c >> 2)) * K + k0 + (c & 3) * 8, &Bs[c * 8]);
        }
        __syncthreads();
        bf16x8 af[MT], bfr[NT];
        #pragma unroll
        for (int i = 0; i < MT; ++i)
            af[i] = *reinterpret_cast<const bf16x8*>(&As[(wm0 + i * 16 + r16) * 32 + quad * 8]);
        #pragma unroll
        for (int j = 0; j < NT; ++j)
            bfr[j] = *reinterpret_cast<const bf16x8*>(&Bs[(wn0 + j * 16 + r16) * 32 + quad * 8]);
        #pragma unroll
        for (int i = 0; i < MT; ++i)
            #pragma unroll
            for (int j = 0; j < NT; ++j)
                acc[i][j] = __builtin_amdgcn_mfma_f32_16x16x32_bf16(
                    af[i], bfr[j], acc[i][j], 0, 0, 0);
        __syncthreads();
    }

    // D layout: col = lane&15, row = quad*4 + reg
    if constexpr (EPI == 2) {
        float xbr[NT][8];
        #pragma unroll
        for (int j = 0; j < NT; ++j) {
            const int nl = wn0 + j * 16 + r16;
            // sample resolved per-row below; preload both halves' xb is per (s,nl):
            // here s varies with row tile; load lazily per i instead.
            (void)nl;
        }
        #pragma unroll
        for (int i = 0; i < MT; ++i) {
            const int mlBase = wm0 + i * 16 + quad * 4;
            const int s = mlBase >> 5;  // constant within a 16-row tile
            #pragma unroll
            for (int j = 0; j < NT; ++j) {
                const int nl = wn0 + j * 16 + r16;
                #pragma unroll
                for (int rr = 0; rr < 8; ++rr)
                    xbr[j][rr] = xbS[(s * BN + nl) * 8 + rr];
            }
            #pragma unroll
            for (int r = 0; r < 4; ++r) {
                const int ml = mlBase + r;
                const int m = bm + ml;
                float t8[8];
                #pragma unroll
                for (int rr = 0; rr < 8; ++rr) t8[rr] = tmS[ml * 8 + rr];
                #pragma unroll
                for (int j = 0; j < NT; ++j) {
                    const int n = bn + wn0 + j * 16 + r16;
                    float v = acc[i][j][r];
                    #pragma unroll
                    for (int rr = 0; rr < 8; ++rr) v += t8[rr] * xbr[j][rr];
                    C[(size_t)m * N + n] = v;
                }
            }
        }
    } else {
        #pragma unroll
        for (int i = 0; i < MT; ++i) {
            #pragma unroll
            for (int r = 0; r < 4; ++r) {
                const int m = bm + wm0 + i * 16 + quad * 4 + r;
                #pragma unroll
                for (int j = 0; j < NT; ++j) {
                    const int n = bn + wn0 + j * 16 + r16;
                    float v = acc[i][j][r];
                    if (EPI == 0) {
                        C[((size_t)blockIdx.z * M + m) * N + n] = v;
                    } else {
                        C[(size_t)m * N + n] = v + bias[n];
                    }
                }
            }
        }
    }
}

// ---------------------------------------------------------------------------
// Combine split-K partials + bias + exact GELU -> h (bf16)
// ---------------------------------------------------------------------------
__global__ __launch_bounds__(256) void combine_gelu(
    const float* __restrict__ part, const float* __restrict__ b1,
    short* __restrict__ h)
{
    const int idx = blockIdx.x * 256 + threadIdx.x;  // < 128*1024
    float s = b1[idx & (NINT - 1)];
    #pragma unroll
    for (int z = 0; z < SPLITS; ++z) s += part[(size_t)z * BB * NINT + idx];
    s = 0.5f * s * (1.f + erff(s * 0.70710678118654752f));
    h[idx] = f2bf(s);
}

// ---------------------------------------------------------------------------
// tmat partials: tp[ch][b][m][r] = sum_{c in chunk} x[b,m,c] * x_a[b,c,r]
// ---------------------------------------------------------------------------
__global__ __launch_bounds__(256) void tpart_kernel(
    const float* __restrict__ x, const float* __restrict__ xw,
    float* __restrict__ tp)
{
    __shared__ float xa[(DD / TKCH) * NRANK];  // 4 KB chunk [c][r]
    const int b = blockIdx.x, ch = blockIdx.y;
    const float* src = xw + (size_t)b * (2 * DD * NRANK) + (size_t)ch * (DD / TKCH) * NRANK;
    float4 v = *(const float4*)(src + threadIdx.x * 4);
    *(float4*)(xa + threadIdx.x * 4) = v;
    __syncthreads();
    const int m = threadIdx.x >> 3;
    const int r = threadIdx.x & 7;
    const float* xrow = x + ((size_t)b * TT + m) * DD + ch * (DD / TKCH);
    float accv = 0.f;
    #pragma unroll 4
    for (int c = 0; c < DD / TKCH; c += 4) {
        float4 xr = *(const float4*)(xrow + c);
        accv += xr.x * xa[(c + 0) * NRANK + r];
        accv += xr.y * xa[(c + 1) * NRANK + r];
        accv += xr.z * xa[(c + 2) * NRANK + r];
        accv += xr.w * xa[(c + 3) * NRANK + r];
    }
    tp[((size_t)ch * BB * TT + (size_t)b * TT + m) * NRANK + r] = accv;
}

__global__ __launch_bounds__(256) void tcomb_kernel(
    const float* __restrict__ tp, float* __restrict__ tm)
{
    const int i = blockIdx.x * 256 + threadIdx.x;  // < 128*32*8
    float s = 0.f;
    #pragma unroll
    for (int ch = 0; ch < TKCH; ++ch) s += tp[(size_t)ch * BB * TT * NRANK + i];
    tm[i] = s;
}

// ---------------------------------------------------------------------------
extern "C" void kernel_launch(void* const* d_in, const int* in_sizes, int n_in,
                              void* d_out, int out_size, void* d_ws, size_t ws_size,
                              hipStream_t stream)
{
    const float* x    = (const float*)d_in[0];  // (128,32,1024)
    const float* ada  = (const float*)d_in[1];  // (128,1024)
    const float* base = (const float*)d_in[2];  // (1024,1024)
    const float* w1   = (const float*)d_in[3];  // (1024,1024)
    const float* b1   = (const float*)d_in[4];  // (1024,)
    const float* w2   = (const float*)d_in[5];  // (1024,16384)
    const float* b2   = (const float*)d_in[6];  // (16384,)
    const float* lng  = (const float*)d_in[7];  // (1024,)
    const float* lnb  = (const float*)d_in[8];  // (1024,)
    float* out = (float*)d_out;

    char* w = (char*)d_ws;
    short* x_bf  = (short*)w;  w += (size_t)8 << 20;   // 4096x1024 bf16
    short* w2t   = (short*)w;  w += (size_t)32 << 20;  // 16384x1024 bf16
    short* w1t   = (short*)w;  w += (size_t)2 << 20;   // 1024x1024 bf16
    short* baset = (short*)w;  w += (size_t)2 << 20;   // 1024x1024 bf16 (base^T + I)
    short* ae_bf = (short*)w;  w += (size_t)256 << 10; // 128x1024 bf16
    short* h_bf  = (short*)w;  w += (size_t)256 << 10; // 128x1024 bf16
    float* xw    = (float*)w;  w += (size_t)8 << 20;   // 128x16384 fp32
    float* tm    = (float*)w;  w += (size_t)128 << 10; // 128x32x8 fp32
    float* part  = (float*)w;                          // 4 MB (aliases tp)
    float* tp    = part;

    // independent pre-casts
    cast_kernel<<<BB * TT * DD / 1024, 256, 0, stream>>>(x, x_bf);
    tcast_kernel<false><<<dim3(NINT / 64, NADA / 64), 256, 0, stream>>>(w1, w1t, NADA, NINT);
    tcast_kernel<true><<<dim3(DD / 64, DD / 64), 256, 0, stream>>>(base, baset, DD, DD);
    tcast_kernel<false><<<dim3(2 * DD * NRANK / 64, NINT / 64), 256, 0, stream>>>(
        w2, w2t, NINT, 2 * DD * NRANK);
    // 1. layernorm -> bf16
    ln_kernel<<<BB, 256, 0, stream>>>(ada, lng, lnb, ae_bf);
    // 2. ae@w1 split-K partials, then gelu(sum+b1) -> h_bf   (grid 256 blocks)
    mgemm<64, 64, 2, 2, 0><<<dim3(NINT / 64, BB / 64, SPLITS), 256, 0, stream>>>(
        ae_bf, w1t, nullptr, part, BB, NINT, NADA, NADA / SPLITS, nullptr, nullptr);
    combine_gelu<<<BB * NINT / 256, 256, 0, stream>>>(part, b1, h_bf);
    // 3. xw = h@w2 + b2   (grid 512 blocks, 2 blocks/CU)
    mgemm<64, 64, 2, 2, 1><<<dim3(2 * DD * NRANK / 64, BB / 64, 1), 256, 0, stream>>>(
        h_bf, w2t, b2, xw, BB, 2 * DD * NRANK, NINT, NINT, nullptr, nullptr);
    // 4. tmat = per-sample x@x_a (split over k, fp32)  (grid 1024 blocks)
    tpart_kernel<<<dim3(BB, TKCH), 256, 0, stream>>>(x, xw, tp);
    tcomb_kernel<<<BB * TT * NRANK / 256, 256, 0, stream>>>(tp, tm);
    // 5. out = x@(base+I) + t@x_b^T   (grid 512 blocks, 2 blocks/CU)
    mgemm<128, 64, 2, 2, 2><<<dim3(DD / 64, BB * TT / 128, 1), 256, 0, stream>>>(
        x_bf, baset, nullptr, out, BB * TT, DD, DD, DD, tm, xw);
}

// Round 5
// 196.446 us; speedup vs baseline: 1.2778x; 1.0070x over previous
//
#include <hip/hip_runtime.h>
#include <hip/hip_bf16.h>
#include <math.h>

// Problem constants
#define BB    128
#define TT    32
#define DD    1024
#define NADA  1024
#define NINT  1024
#define NRANK 8
#define LNEPS 1e-5f
#define TKCH  8   // tmat k-chunks

using bf16x8 = __attribute__((ext_vector_type(8))) short;
using f32x4  = __attribute__((ext_vector_type(4))) float;

__device__ __forceinline__ short f2bf(float f) {
    __hip_bfloat16 h = __float2bfloat16(f);  // RNE
    return *reinterpret_cast<short*>(&h);
}

__device__ __forceinline__ void async16(const void* g, void* l) {
    __builtin_amdgcn_global_load_lds(
        (const __attribute__((address_space(1))) void*)g,
        (__attribute__((address_space(3))) void*)l, 16, 0, 0);
}

// ---------------------------------------------------------------------------
// Mega prep kernel: one launch does all independent preprocessing.
//   blocks [0, 4096)      : w2  (1024,16384) -> w2t  (16384,1024) bf16
//   blocks [4096, 6144)   : x cast -> bf16 (2 float4 / thread)
//   blocks [6144, 6400)   : w1  (1024,1024)  -> w1t  bf16
//   blocks [6400, 6656)   : base+I           -> baset bf16
//   blocks [6656, 6784)   : LayerNorm(ada) -> ae_bf
// ---------------------------------------------------------------------------
__device__ __forceinline__ void tcast_tile(
    const float* __restrict__ in, short* __restrict__ out, int K, int N,
    int bx, int by, bool addI, int tid, float (*t)[68])
{
    const int n0 = bx * 64, k0 = by * 64;
    #pragma unroll
    for (int it = 0; it < 4; ++it) {
        const int idx = it * 256 + tid;
        const int r = idx >> 4, c4 = (idx & 15) * 4;
        float4 v = *(const float4*)(in + (size_t)(k0 + r) * N + n0 + c4);
        t[r][c4 + 0] = v.x; t[r][c4 + 1] = v.y;
        t[r][c4 + 2] = v.z; t[r][c4 + 3] = v.w;
    }
    __syncthreads();
    #pragma unroll
    for (int it = 0; it < 4; ++it) {
        const int idx = it * 256 + tid;
        const int rn = idx >> 4, c4 = (idx & 15) * 4;
        float f0 = t[c4 + 0][rn], f1 = t[c4 + 1][rn];
        float f2 = t[c4 + 2][rn], f3 = t[c4 + 3][rn];
        if (addI) {
            const int n = n0 + rn;
            if (k0 + c4 + 0 == n) f0 += 1.f;
            if (k0 + c4 + 1 == n) f1 += 1.f;
            if (k0 + c4 + 2 == n) f2 += 1.f;
            if (k0 + c4 + 3 == n) f3 += 1.f;
        }
        short4 p;
        p.x = f2bf(f0); p.y = f2bf(f1); p.z = f2bf(f2); p.w = f2bf(f3);
        *(short4*)(out + (size_t)(n0 + rn) * K + k0 + c4) = p;
    }
}

__global__ __launch_bounds__(256) void prep_kernel(
    const float* __restrict__ x, const float* __restrict__ w1,
    const float* __restrict__ base, const float* __restrict__ w2,
    const float* __restrict__ ada, const float* __restrict__ lng,
    const float* __restrict__ lnb,
    short* __restrict__ x_bf, short* __restrict__ w1t,
    short* __restrict__ baset, short* __restrict__ w2t,
    short* __restrict__ ae_bf)
{
    __shared__ float t[64][68];
    const int bid = blockIdx.x, tid = threadIdx.x;

    if (bid < 4096) {
        tcast_tile(w2, w2t, NINT, 2 * DD * NRANK, bid & 255, bid >> 8, false, tid, t);
    } else if (bid < 6144) {
        const int b = bid - 4096;
        const int i0 = b * 512 + tid;
        float4 v0 = reinterpret_cast<const float4*>(x)[i0];
        float4 v1 = reinterpret_cast<const float4*>(x)[i0 + 256];
        short4 p0, p1;
        p0.x = f2bf(v0.x); p0.y = f2bf(v0.y); p0.z = f2bf(v0.z); p0.w = f2bf(v0.w);
        p1.x = f2bf(v1.x); p1.y = f2bf(v1.y); p1.z = f2bf(v1.z); p1.w = f2bf(v1.w);
        reinterpret_cast<short4*>(x_bf)[i0] = p0;
        reinterpret_cast<short4*>(x_bf)[i0 + 256] = p1;
    } else if (bid < 6400) {
        const int b = bid - 6144;
        tcast_tile(w1, w1t, NADA, NINT, b & 15, b >> 4, false, tid, t);
    } else if (bid < 6656) {
        const int b = bid - 6400;
        tcast_tile(base, baset, DD, DD, b & 15, b >> 4, true, tid, t);
    } else {
        // LayerNorm, one block per sample
        const int b = bid - 6656;
        const float* row = ada + (size_t)b * NADA;
        float sum = 0.f, sumsq = 0.f;
        for (int i = tid; i < NADA; i += 256) {
            float v = row[i];
            sum += v; sumsq += v * v;
        }
        #pragma unroll
        for (int off = 32; off > 0; off >>= 1) {
            sum   += __shfl_down(sum, off);
            sumsq += __shfl_down(sumsq, off);
        }
        float* s1 = &t[0][0];
        float* s2 = &t[1][0];
        const int wid = tid >> 6, lane = tid & 63;
        if (lane == 0) { s1[wid] = sum; s2[wid] = sumsq; }
        __syncthreads();
        if (tid == 0) {
            float a = 0.f, c = 0.f;
            for (int i = 0; i < 4; ++i) { a += s1[i]; c += s2[i]; }
            s1[0] = a; s2[0] = c;
        }
        __syncthreads();
        const float mu  = s1[0] * (1.f / NADA);
        const float var = s2[0] * (1.f / NADA) - mu * mu;
        const float inv = rsqrtf(var + LNEPS);
        for (int i = tid; i < NADA; i += 256) {
            ae_bf[(size_t)b * NADA + i] = f2bf((row[i] - mu) * inv * lng[i] + lnb[i]);
        }
    }
}

// ---------------------------------------------------------------------------
// bf16 MFMA GEMM. A (M,K) bf16 row-major, Bt (N,K) bf16 row-major.
// async global->LDS staging, ds_read_b128 fragments, WMxWN wave grid.
// EPI==1: C = acc + bias (fp32)
// EPI==2: C = acc + rank-8 LoRA; tmat = tp chunk-sum in prologue (fp32)
// EPI==3: C = f2bf(gelu(acc + bias))  (bf16 out)
// ---------------------------------------------------------------------------
template <int BM, int BN, int WM, int WN, int EPI>
__global__ __launch_bounds__(256, 2) void mgemm(
    const short* __restrict__ A, const short* __restrict__ Bt,
    const float* __restrict__ bias, float* __restrict__ C,
    int M, int N, int K, int kLen,
    const float* __restrict__ tp, const float* __restrict__ xw)
{
    constexpr int MT = BM / WM / 16;
    constexpr int NT = BN / WN / 16;
    constexpr int LA = BM / 64;   // async16 per thread for A tile
    constexpr int LB = BN / 64;

    __shared__ __align__(16) short As[BM * 32];
    __shared__ __align__(16) short Bs[BN * 32];
    __shared__ float tmS[(EPI == 2) ? BM * 8 : 1];
    __shared__ float xbS[(EPI == 2) ? (BM / 32) * BN * 8 : 1];

    const int bm = blockIdx.y * BM;
    const int bn = blockIdx.x * BN;
    const int tid = threadIdx.x;
    const int wave = tid >> 6, lane = tid & 63;
    const int wm0 = (wave / WN) * (BM / WM);
    const int wn0 = (wave % WN) * (BN / WN);
    const int quad = lane >> 4, r16 = lane & 15;

    if constexpr (EPI == 2) {
        // tmS = sum of TKCH split-K chunks of tp for rows [bm, bm+BM)
        float4 a = {0.f, 0.f, 0.f, 0.f};
        #pragma unroll
        for (int ch = 0; ch < TKCH; ++ch) {
            float4 v = *(const float4*)(tp + (size_t)ch * BB * TT * NRANK
                                           + (size_t)bm * 8 + tid * 4);
            a.x += v.x; a.y += v.y; a.z += v.z; a.w += v.w;
        }
        *(float4*)&tmS[tid * 4] = a;
        // stage x_b slice: (BM/32) samples x BN cols x 8
        const int b0 = bm >> 5;
        const int grp = tid >> 6;
        const int inner = tid & 63;
        const float* src = xw + (size_t)(b0 + grp) * (2 * DD * NRANK) + DD * NRANK
                              + (size_t)bn * 8;
        *(float4*)&xbS[grp * BN * 8 + inner * 8]     = *(const float4*)(src + inner * 8);
        *(float4*)&xbS[grp * BN * 8 + inner * 8 + 4] = *(const float4*)(src + inner * 8 + 4);
    }

    f32x4 acc[MT][NT] = {};

    for (int k0 = 0; k0 < kLen; k0 += 32) {
        #pragma unroll
        for (int s = 0; s < LA; ++s) {
            const int c = s * 256 + tid;
            async16(A + (size_t)(bm + (c >> 2)) * K + k0 + (c & 3) * 8, &As[c * 8]);
        }
        #pragma unroll
        for (int s = 0; s < LB; ++s) {
            const int c = s * 256 + tid;
            async16(Bt + (size_t)(bn + (c >> 2)) * K + k0 + (c & 3) * 8, &Bs[c * 8]);
        }
        __syncthreads();
        bf16x8 af[MT], bfr[NT];
        #pragma unroll
        for (int i = 0; i < MT; ++i)
            af[i] = *reinterpret_cast<const bf16x8*>(&As[(wm0 + i * 16 + r16) * 32 + quad * 8]);
        #pragma unroll
        for (int j = 0; j < NT; ++j)
            bfr[j] = *reinterpret_cast<const bf16x8*>(&Bs[(wn0 + j * 16 + r16) * 32 + quad * 8]);
        #pragma unroll
        for (int i = 0; i < MT; ++i)
            #pragma unroll
            for (int j = 0; j < NT; ++j)
                acc[i][j] = __builtin_amdgcn_mfma_f32_16x16x32_bf16(
                    af[i], bfr[j], acc[i][j], 0, 0, 0);
        __syncthreads();
    }

    // D layout: col = lane&15, row = quad*4 + reg
    if constexpr (EPI == 2) {
        float xbr[NT][8];
        #pragma unroll
        for (int i = 0; i < MT; ++i) {
            const int mlBase = wm0 + i * 16 + quad * 4;
            const int s = mlBase >> 5;  // constant within a 16-row tile
            #pragma unroll
            for (int j = 0; j < NT; ++j) {
                const int nl = wn0 + j * 16 + r16;
                #pragma unroll
                for (int rr = 0; rr < 8; ++rr)
                    xbr[j][rr] = xbS[(s * BN + nl) * 8 + rr];
            }
            #pragma unroll
            for (int r = 0; r < 4; ++r) {
                const int ml = mlBase + r;
                const int m = bm + ml;
                float t8[8];
                #pragma unroll
                for (int rr = 0; rr < 8; ++rr) t8[rr] = tmS[ml * 8 + rr];
                #pragma unroll
                for (int j = 0; j < NT; ++j) {
                    const int n = bn + wn0 + j * 16 + r16;
                    float v = acc[i][j][r];
                    #pragma unroll
                    for (int rr = 0; rr < 8; ++rr) v += t8[rr] * xbr[j][rr];
                    C[(size_t)m * N + n] = v;
                }
            }
        }
    } else {
        #pragma unroll
        for (int i = 0; i < MT; ++i) {
            #pragma unroll
            for (int r = 0; r < 4; ++r) {
                const int m = bm + wm0 + i * 16 + quad * 4 + r;
                #pragma unroll
                for (int j = 0; j < NT; ++j) {
                    const int n = bn + wn0 + j * 16 + r16;
                    float v = acc[i][j][r] + bias[n];
                    if (EPI == 1) {
                        C[(size_t)m * N + n] = v;
                    } else {  // EPI == 3: exact GELU, bf16 out
                        v = 0.5f * v * (1.f + erff(v * 0.70710678118654752f));
                        ((short*)C)[(size_t)m * N + n] = f2bf(v);
                    }
                }
            }
        }
    }
}

// ---------------------------------------------------------------------------
// tmat partials: tp[ch][b][m][r] = sum_{c in chunk} x[b,m,c] * x_a[b,c,r]
// ---------------------------------------------------------------------------
__global__ __launch_bounds__(256) void tpart_kernel(
    const float* __restrict__ x, const float* __restrict__ xw,
    float* __restrict__ tp)
{
    __shared__ float xa[(DD / TKCH) * NRANK];  // 4 KB chunk [c][r]
    const int b = blockIdx.x, ch = blockIdx.y;
    const float* src = xw + (size_t)b * (2 * DD * NRANK) + (size_t)ch * (DD / TKCH) * NRANK;
    float4 v = *(const float4*)(src + threadIdx.x * 4);
    *(float4*)(xa + threadIdx.x * 4) = v;
    __syncthreads();
    const int m = threadIdx.x >> 3;
    const int r = threadIdx.x & 7;
    const float* xrow = x + ((size_t)b * TT + m) * DD + ch * (DD / TKCH);
    float accv = 0.f;
    #pragma unroll 4
    for (int c = 0; c < DD / TKCH; c += 4) {
        float4 xr = *(const float4*)(xrow + c);
        accv += xr.x * xa[(c + 0) * NRANK + r];
        accv += xr.y * xa[(c + 1) * NRANK + r];
        accv += xr.z * xa[(c + 2) * NRANK + r];
        accv += xr.w * xa[(c + 3) * NRANK + r];
    }
    tp[((size_t)ch * BB * TT + (size_t)b * TT + m) * NRANK + r] = accv;
}

// ---------------------------------------------------------------------------
extern "C" void kernel_launch(void* const* d_in, const int* in_sizes, int n_in,
                              void* d_out, int out_size, void* d_ws, size_t ws_size,
                              hipStream_t stream)
{
    const float* x    = (const float*)d_in[0];  // (128,32,1024)
    const float* ada  = (const float*)d_in[1];  // (128,1024)
    const float* base = (const float*)d_in[2];  // (1024,1024)
    const float* w1   = (const float*)d_in[3];  // (1024,1024)
    const float* b1   = (const float*)d_in[4];  // (1024,)
    const float* w2   = (const float*)d_in[5];  // (1024,16384)
    const float* b2   = (const float*)d_in[6];  // (16384,)
    const float* lng  = (const float*)d_in[7];  // (1024,)
    const float* lnb  = (const float*)d_in[8];  // (1024,)
    float* out = (float*)d_out;

    char* w = (char*)d_ws;
    short* x_bf  = (short*)w;  w += (size_t)8 << 20;   // 4096x1024 bf16
    short* w2t   = (short*)w;  w += (size_t)32 << 20;  // 16384x1024 bf16
    short* w1t   = (short*)w;  w += (size_t)2 << 20;   // 1024x1024 bf16
    short* baset = (short*)w;  w += (size_t)2 << 20;   // 1024x1024 bf16 (base^T + I)
    short* ae_bf = (short*)w;  w += (size_t)256 << 10; // 128x1024 bf16
    short* h_bf  = (short*)w;  w += (size_t)256 << 10; // 128x1024 bf16
    float* xw    = (float*)w;  w += (size_t)8 << 20;   // 128x16384 fp32
    float* tp    = (float*)w;                          // 8x128x32x8 fp32 (1 MB)

    // 1. all preprocessing in one launch (6784 blocks)
    prep_kernel<<<6784, 256, 0, stream>>>(
        x, w1, base, w2, ada, lng, lnb, x_bf, w1t, baset, w2t, ae_bf);
    // 2. h = gelu(ae@w1 + b1) -> bf16   (grid 32 blocks)
    mgemm<64, 64, 2, 2, 3><<<dim3(NINT / 64, BB / 64), 256, 0, stream>>>(
        ae_bf, w1t, b1, (float*)h_bf, BB, NINT, NADA, NADA, nullptr, nullptr);
    // 3. xw = h@w2 + b2   (grid 512 blocks)
    mgemm<64, 64, 2, 2, 1><<<dim3(2 * DD * NRANK / 64, BB / 64), 256, 0, stream>>>(
        h_bf, w2t, b2, xw, BB, 2 * DD * NRANK, NINT, NINT, nullptr, nullptr);
    // 4. tmat split-K partials   (grid 1024 blocks)
    tpart_kernel<<<dim3(BB, TKCH), 256, 0, stream>>>(x, xw, tp);
    // 5. out = x@(base+I) + t@x_b^T; tp summed in prologue  (grid 512 blocks)
    mgemm<128, 64, 2, 2, 2><<<dim3(DD / 64, BB * TT / 128), 256, 0, stream>>>(
        x_bf, baset, nullptr, out, BB * TT, DD, DD, DD, tp, xw);
}

// Round 6
// 189.612 us; speedup vs baseline: 1.3239x; 1.0360x over previous
//
#include <hip/hip_runtime.h>
#include <hip/hip_bf16.h>
#include <math.h>

// Problem constants
#define BB    128
#define TT    32
#define DD    1024
#define NADA  1024
#define NINT  1024
#define NRANK 8
#define LNEPS 1e-5f
#define TKCH  8   // tmat k-chunks
#define SPL2  4   // gemm2 k-splits

using bf16x8 = __attribute__((ext_vector_type(8))) short;
using f32x4  = __attribute__((ext_vector_type(4))) float;

__device__ __forceinline__ short f2bf(float f) {
    __hip_bfloat16 h = __float2bfloat16(f);  // RNE
    return *reinterpret_cast<short*>(&h);
}

__device__ __forceinline__ void async16(const void* g, void* l) {
    __builtin_amdgcn_global_load_lds(
        (const __attribute__((address_space(1))) void*)g,
        (__attribute__((address_space(3))) void*)l, 16, 0, 0);
}

// ---------------------------------------------------------------------------
// Mega prep kernel (one launch, all independent preprocessing):
//   [0, 2048)     : x cast -> bf16
//   [2048, 2304)  : w1 -> w1t bf16
//   [2304, 2560)  : base+I -> baset bf16
//   [2560, 2688)  : LayerNorm(ada) -> ae_bf
//   [2688, 4736)  : xw init = broadcast b2 (fp32, for gemm3 atomics)
// ---------------------------------------------------------------------------
__device__ __forceinline__ void tcast_tile(
    const float* __restrict__ in, short* __restrict__ out, int K, int N,
    int bx, int by, bool addI, int tid, float (*t)[68])
{
    const int n0 = bx * 64, k0 = by * 64;
    #pragma unroll
    for (int it = 0; it < 4; ++it) {
        const int idx = it * 256 + tid;
        const int r = idx >> 4, c4 = (idx & 15) * 4;
        float4 v = *(const float4*)(in + (size_t)(k0 + r) * N + n0 + c4);
        t[r][c4 + 0] = v.x; t[r][c4 + 1] = v.y;
        t[r][c4 + 2] = v.z; t[r][c4 + 3] = v.w;
    }
    __syncthreads();
    #pragma unroll
    for (int it = 0; it < 4; ++it) {
        const int idx = it * 256 + tid;
        const int rn = idx >> 4, c4 = (idx & 15) * 4;
        float f0 = t[c4 + 0][rn], f1 = t[c4 + 1][rn];
        float f2 = t[c4 + 2][rn], f3 = t[c4 + 3][rn];
        if (addI) {
            const int n = n0 + rn;
            if (k0 + c4 + 0 == n) f0 += 1.f;
            if (k0 + c4 + 1 == n) f1 += 1.f;
            if (k0 + c4 + 2 == n) f2 += 1.f;
            if (k0 + c4 + 3 == n) f3 += 1.f;
        }
        short4 p;
        p.x = f2bf(f0); p.y = f2bf(f1); p.z = f2bf(f2); p.w = f2bf(f3);
        *(short4*)(out + (size_t)(n0 + rn) * K + k0 + c4) = p;
    }
}

__global__ __launch_bounds__(256) void prep_kernel(
    const float* __restrict__ x, const float* __restrict__ w1,
    const float* __restrict__ base, const float* __restrict__ ada,
    const float* __restrict__ lng, const float* __restrict__ lnb,
    const float* __restrict__ b2,
    short* __restrict__ x_bf, short* __restrict__ w1t,
    short* __restrict__ baset, short* __restrict__ ae_bf,
    float* __restrict__ xw)
{
    __shared__ float t[64][68];
    const int bid = blockIdx.x, tid = threadIdx.x;

    if (bid < 2048) {
        const int i0 = bid * 512 + tid;
        float4 v0 = reinterpret_cast<const float4*>(x)[i0];
        float4 v1 = reinterpret_cast<const float4*>(x)[i0 + 256];
        short4 p0, p1;
        p0.x = f2bf(v0.x); p0.y = f2bf(v0.y); p0.z = f2bf(v0.z); p0.w = f2bf(v0.w);
        p1.x = f2bf(v1.x); p1.y = f2bf(v1.y); p1.z = f2bf(v1.z); p1.w = f2bf(v1.w);
        reinterpret_cast<short4*>(x_bf)[i0] = p0;
        reinterpret_cast<short4*>(x_bf)[i0 + 256] = p1;
    } else if (bid < 2304) {
        const int b = bid - 2048;
        tcast_tile(w1, w1t, NADA, NINT, b & 15, b >> 4, false, tid, t);
    } else if (bid < 2560) {
        const int b = bid - 2304;
        tcast_tile(base, baset, DD, DD, b & 15, b >> 4, true, tid, t);
    } else if (bid < 2688) {
        // LayerNorm, one block per sample
        const int b = bid - 2560;
        const float* row = ada + (size_t)b * NADA;
        float sum = 0.f, sumsq = 0.f;
        for (int i = tid; i < NADA; i += 256) {
            float v = row[i];
            sum += v; sumsq += v * v;
        }
        #pragma unroll
        for (int off = 32; off > 0; off >>= 1) {
            sum   += __shfl_down(sum, off);
            sumsq += __shfl_down(sumsq, off);
        }
        float* s1 = &t[0][0];
        float* s2 = &t[1][0];
        const int wid = tid >> 6, lane = tid & 63;
        if (lane == 0) { s1[wid] = sum; s2[wid] = sumsq; }
        __syncthreads();
        if (tid == 0) {
            float a = 0.f, c = 0.f;
            for (int i = 0; i < 4; ++i) { a += s1[i]; c += s2[i]; }
            s1[0] = a; s2[0] = c;
        }
        __syncthreads();
        const float mu  = s1[0] * (1.f / NADA);
        const float var = s2[0] * (1.f / NADA) - mu * mu;
        const float inv = rsqrtf(var + LNEPS);
        for (int i = tid; i < NADA; i += 256) {
            ae_bf[(size_t)b * NADA + i] = f2bf((row[i] - mu) * inv * lng[i] + lnb[i]);
        }
    } else {
        // xw[m][n] = b2[n]
        const int i0 = (bid - 2688) * 1024 + tid * 4;     // flat f32 index
        const int n0 = i0 & (2 * DD * NRANK - 1);
        *(float4*)(xw + i0) = *(const float4*)(b2 + n0);
    }
}

// ---------------------------------------------------------------------------
// bf16 MFMA GEMM (pre-transposed bf16 B). A (M,K), Bt (N,K) bf16 row-major.
// EPI==0: partial to C[z][M][N] (split-K)
// EPI==2: C = acc + rank-8 LoRA; tmat = tp chunk-sum in prologue (fp32)
// ---------------------------------------------------------------------------
template <int BM, int BN, int WM, int WN, int EPI>
__global__ __launch_bounds__(256, 2) void mgemm(
    const short* __restrict__ A, const short* __restrict__ Bt,
    float* __restrict__ C, int M, int N, int K, int kLen,
    const float* __restrict__ tp, const float* __restrict__ xw)
{
    constexpr int MT = BM / WM / 16;
    constexpr int NT = BN / WN / 16;
    constexpr int LA = BM / 64;
    constexpr int LB = BN / 64;

    __shared__ __align__(16) short As[BM * 32];
    __shared__ __align__(16) short Bs[BN * 32];
    __shared__ float tmS[(EPI == 2) ? BM * 8 : 1];
    __shared__ float xbS[(EPI == 2) ? (BM / 32) * BN * 8 : 1];

    const int bm = blockIdx.y * BM;
    const int bn = blockIdx.x * BN;
    const int kStart = blockIdx.z * kLen;
    const int tid = threadIdx.x;
    const int wave = tid >> 6, lane = tid & 63;
    const int wm0 = (wave / WN) * (BM / WM);
    const int wn0 = (wave % WN) * (BN / WN);
    const int quad = lane >> 4, r16 = lane & 15;

    if constexpr (EPI == 2) {
        float4 a = {0.f, 0.f, 0.f, 0.f};
        #pragma unroll
        for (int ch = 0; ch < TKCH; ++ch) {
            float4 v = *(const float4*)(tp + (size_t)ch * BB * TT * NRANK
                                           + (size_t)bm * 8 + tid * 4);
            a.x += v.x; a.y += v.y; a.z += v.z; a.w += v.w;
        }
        *(float4*)&tmS[tid * 4] = a;
        const int b0 = bm >> 5;
        const int grp = tid >> 6;
        const int inner = tid & 63;
        const float* src = xw + (size_t)(b0 + grp) * (2 * DD * NRANK) + DD * NRANK
                              + (size_t)bn * 8;
        *(float4*)&xbS[grp * BN * 8 + inner * 8]     = *(const float4*)(src + inner * 8);
        *(float4*)&xbS[grp * BN * 8 + inner * 8 + 4] = *(const float4*)(src + inner * 8 + 4);
    }

    f32x4 acc[MT][NT] = {};

    for (int kt = 0; kt < kLen; kt += 32) {
        const int k0 = kStart + kt;
        #pragma unroll
        for (int s = 0; s < LA; ++s) {
            const int c = s * 256 + tid;
            async16(A + (size_t)(bm + (c >> 2)) * K + k0 + (c & 3) * 8, &As[c * 8]);
        }
        #pragma unroll
        for (int s = 0; s < LB; ++s) {
            const int c = s * 256 + tid;
            async16(Bt + (size_t)(bn + (c >> 2)) * K + k0 + (c & 3) * 8, &Bs[c * 8]);
        }
        __syncthreads();
        bf16x8 af[MT], bfr[NT];
        #pragma unroll
        for (int i = 0; i < MT; ++i)
            af[i] = *reinterpret_cast<const bf16x8*>(&As[(wm0 + i * 16 + r16) * 32 + quad * 8]);
        #pragma unroll
        for (int j = 0; j < NT; ++j)
            bfr[j] = *reinterpret_cast<const bf16x8*>(&Bs[(wn0 + j * 16 + r16) * 32 + quad * 8]);
        #pragma unroll
        for (int i = 0; i < MT; ++i)
            #pragma unroll
            for (int j = 0; j < NT; ++j)
                acc[i][j] = __builtin_amdgcn_mfma_f32_16x16x32_bf16(
                    af[i], bfr[j], acc[i][j], 0, 0, 0);
        __syncthreads();
    }

    // D layout: col = lane&15, row = quad*4 + reg
    if constexpr (EPI == 2) {
        float xbr[NT][8];
        #pragma unroll
        for (int i = 0; i < MT; ++i) {
            const int mlBase = wm0 + i * 16 + quad * 4;
            const int s = mlBase >> 5;
            #pragma unroll
            for (int j = 0; j < NT; ++j) {
                const int nl = wn0 + j * 16 + r16;
                #pragma unroll
                for (int rr = 0; rr < 8; ++rr)
                    xbr[j][rr] = xbS[(s * BN + nl) * 8 + rr];
            }
            #pragma unroll
            for (int r = 0; r < 4; ++r) {
                const int ml = mlBase + r;
                const int m = bm + ml;
                float t8[8];
                #pragma unroll
                for (int rr = 0; rr < 8; ++rr) t8[rr] = tmS[ml * 8 + rr];
                #pragma unroll
                for (int j = 0; j < NT; ++j) {
                    const int n = bn + wn0 + j * 16 + r16;
                    float v = acc[i][j][r];
                    #pragma unroll
                    for (int rr = 0; rr < 8; ++rr) v += t8[rr] * xbr[j][rr];
                    C[(size_t)m * N + n] = v;
                }
            }
        }
    } else {
        #pragma unroll
        for (int i = 0; i < MT; ++i) {
            #pragma unroll
            for (int r = 0; r < 4; ++r) {
                const int m = bm + wm0 + i * 16 + quad * 4 + r;
                #pragma unroll
                for (int j = 0; j < NT; ++j) {
                    const int n = bn + wn0 + j * 16 + r16;
                    C[((size_t)blockIdx.z * M + m) * N + n] = acc[i][j][r];
                }
            }
        }
    }
}

// ---------------------------------------------------------------------------
// gemm3 fused: xw += h_bf @ w2 (w2 read NATIVE (K,N) fp32; transpose+cast done
// read-side in LDS). Split-K over blockIdx.z, fp32 atomicAdd epilogue into
// xw pre-initialized with b2. Grid (256, 1, SPLITK) = 512 blocks.
// ---------------------------------------------------------------------------
template <int SPLITK>
__global__ __launch_bounds__(256, 2) void gemm_w2(
    const short* __restrict__ A, const float* __restrict__ W,
    float* __restrict__ C, int M, int N, int K)
{
    constexpr int BM = 128, BN = 64;
    constexpr int MT = 4, NT = 2;
    __shared__ __align__(16) short As[BM * 32];   // 8 KB bf16 [m][k]
    __shared__ __align__(16) float Bf[32 * BN];   // 8 KB fp32 [k][n] (native)

    const int bn = blockIdx.x * BN;
    const int kLen = K / SPLITK;
    const int kStart = blockIdx.z * kLen;
    const int tid = threadIdx.x;
    const int wave = tid >> 6, lane = tid & 63;
    const int wm0 = (wave >> 1) * 64;
    const int wn0 = (wave & 1) * 32;
    const int quad = lane >> 4, r16 = lane & 15;

    f32x4 acc[MT][NT] = {};

    for (int kt = 0; kt < kLen; kt += 32) {
        const int k0 = kStart + kt;
        #pragma unroll
        for (int s = 0; s < 2; ++s) {   // A: 128x32 bf16
            const int c = s * 256 + tid;
            async16(A + (size_t)(c >> 2) * K + k0 + (c & 3) * 8, &As[c * 8]);
        }
        #pragma unroll
        for (int s = 0; s < 2; ++s) {   // B: 32x64 fp32, native layout
            const int c = s * 256 + tid;
            async16(W + (size_t)(k0 + (c >> 4)) * N + bn + (c & 15) * 4, &Bf[c * 4]);
        }
        __syncthreads();
        bf16x8 af[MT], bfr[NT];
        #pragma unroll
        for (int i = 0; i < MT; ++i)
            af[i] = *reinterpret_cast<const bf16x8*>(&As[(wm0 + i * 16 + r16) * 32 + quad * 8]);
        #pragma unroll
        for (int j = 0; j < NT; ++j) {
            const int n = wn0 + j * 16 + r16;
            short tmp[8];
            #pragma unroll
            for (int t = 0; t < 8; ++t)
                tmp[t] = f2bf(Bf[(quad * 8 + t) * BN + n]);   // read-side transpose
            bfr[j] = *reinterpret_cast<const bf16x8*>(tmp);
        }
        #pragma unroll
        for (int i = 0; i < MT; ++i)
            #pragma unroll
            for (int j = 0; j < NT; ++j)
                acc[i][j] = __builtin_amdgcn_mfma_f32_16x16x32_bf16(
                    af[i], bfr[j], acc[i][j], 0, 0, 0);
        __syncthreads();
    }

    #pragma unroll
    for (int i = 0; i < MT; ++i) {
        #pragma unroll
        for (int r = 0; r < 4; ++r) {
            const int m = wm0 + i * 16 + quad * 4 + r;
            #pragma unroll
            for (int j = 0; j < NT; ++j) {
                const int n = bn + wn0 + j * 16 + r16;
                atomicAdd(&C[(size_t)m * N + n], acc[i][j][r]);
            }
        }
    }
}

// ---------------------------------------------------------------------------
// Combine gemm2 split-K partials + bias + exact GELU -> h (bf16)
// ---------------------------------------------------------------------------
__global__ __launch_bounds__(256) void combine_gelu(
    const float* __restrict__ part, const float* __restrict__ b1,
    short* __restrict__ h)
{
    const int idx = blockIdx.x * 256 + threadIdx.x;  // < 128*1024
    float s = b1[idx & (NINT - 1)];
    #pragma unroll
    for (int z = 0; z < SPL2; ++z) s += part[(size_t)z * BB * NINT + idx];
    s = 0.5f * s * (1.f + erff(s * 0.70710678118654752f));
    h[idx] = f2bf(s);
}

// ---------------------------------------------------------------------------
// tmat partials: tp[ch][b][m][r] = sum_{c in chunk} x[b,m,c] * x_a[b,c,r]
// ---------------------------------------------------------------------------
__global__ __launch_bounds__(256) void tpart_kernel(
    const float* __restrict__ x, const float* __restrict__ xw,
    float* __restrict__ tp)
{
    __shared__ float xa[(DD / TKCH) * NRANK];
    const int b = blockIdx.x, ch = blockIdx.y;
    const float* src = xw + (size_t)b * (2 * DD * NRANK) + (size_t)ch * (DD / TKCH) * NRANK;
    float4 v = *(const float4*)(src + threadIdx.x * 4);
    *(float4*)(xa + threadIdx.x * 4) = v;
    __syncthreads();
    const int m = threadIdx.x >> 3;
    const int r = threadIdx.x & 7;
    const float* xrow = x + ((size_t)b * TT + m) * DD + ch * (DD / TKCH);
    float accv = 0.f;
    #pragma unroll 4
    for (int c = 0; c < DD / TKCH; c += 4) {
        float4 xr = *(const float4*)(xrow + c);
        accv += xr.x * xa[(c + 0) * NRANK + r];
        accv += xr.y * xa[(c + 1) * NRANK + r];
        accv += xr.z * xa[(c + 2) * NRANK + r];
        accv += xr.w * xa[(c + 3) * NRANK + r];
    }
    tp[((size_t)ch * BB * TT + (size_t)b * TT + m) * NRANK + r] = accv;
}

// ---------------------------------------------------------------------------
extern "C" void kernel_launch(void* const* d_in, const int* in_sizes, int n_in,
                              void* d_out, int out_size, void* d_ws, size_t ws_size,
                              hipStream_t stream)
{
    const float* x    = (const float*)d_in[0];
    const float* ada  = (const float*)d_in[1];
    const float* base = (const float*)d_in[2];
    const float* w1   = (const float*)d_in[3];
    const float* b1   = (const float*)d_in[4];
    const float* w2   = (const float*)d_in[5];
    const float* b2   = (const float*)d_in[6];
    const float* lng  = (const float*)d_in[7];
    const float* lnb  = (const float*)d_in[8];
    float* out = (float*)d_out;

    char* w = (char*)d_ws;
    short* x_bf  = (short*)w;  w += (size_t)8 << 20;   // 4096x1024 bf16
    short* w1t   = (short*)w;  w += (size_t)2 << 20;   // 1024x1024 bf16
    short* baset = (short*)w;  w += (size_t)2 << 20;   // 1024x1024 bf16 (base^T + I)
    short* ae_bf = (short*)w;  w += (size_t)256 << 10; // 128x1024 bf16
    short* h_bf  = (short*)w;  w += (size_t)256 << 10; // 128x1024 bf16
    float* xw    = (float*)w;  w += (size_t)8 << 20;   // 128x16384 fp32
    float* tp    = (float*)w;  w += (size_t)1 << 20;   // 8x128x32x8 fp32
    float* part  = (float*)w;                          // 4x128x1024 fp32 (2 MB)

    // 1. all preprocessing + xw=b2 init in one launch (4736 blocks)
    prep_kernel<<<4736, 256, 0, stream>>>(
        x, w1, base, ada, lng, lnb, b2, x_bf, w1t, baset, ae_bf, xw);
    // 2. ae@w1 split-K partials (grid 16x2x4 = 128 blocks), then gelu+bias
    mgemm<64, 64, 2, 2, 0><<<dim3(NINT / 64, BB / 64, SPL2), 256, 0, stream>>>(
        ae_bf, w1t, part, BB, NINT, NADA, NADA / SPL2, nullptr, nullptr);
    combine_gelu<<<BB * NINT / 256, 256, 0, stream>>>(part, b1, h_bf);
    // 3. xw += h@w2 (native-layout w2, read-side transpose; 256x2 = 512 blocks)
    gemm_w2<2><<<dim3(2 * DD * NRANK / 64, 1, 2), 256, 0, stream>>>(
        h_bf, w2, xw, BB, 2 * DD * NRANK, NINT);
    // 4. tmat split-K partials (1024 blocks)
    tpart_kernel<<<dim3(BB, TKCH), 256, 0, stream>>>(x, xw, tp);
    // 5. out = x@(base+I) + t@x_b^T (512 blocks)
    mgemm<128, 64, 2, 2, 2><<<dim3(DD / 64, BB * TT / 128), 256, 0, stream>>>(
        x_bf, baset, out, BB * TT, DD, DD, DD, tp, xw);
}

// Round 7
// 182.139 us; speedup vs baseline: 1.3782x; 1.0410x over previous
//
#include <hip/hip_runtime.h>
#include <hip/hip_bf16.h>
#include <math.h>

// Problem constants
#define BB    128
#define TT    32
#define DD    1024
#define NADA  1024
#define NINT  1024
#define NRANK 8
#define LNEPS 1e-5f
#define TKCH  8   // tmat k-chunks
#define SPL2  4   // gemm2 k-splits
#define SPLW  2   // gemm_w2 k-splits
#define XWN   (2 * DD * NRANK)   // 16384

using bf16x8 = __attribute__((ext_vector_type(8))) short;
using f32x4  = __attribute__((ext_vector_type(4))) float;

__device__ __forceinline__ short f2bf(float f) {
    __hip_bfloat16 h = __float2bfloat16(f);  // RNE
    return *reinterpret_cast<short*>(&h);
}

__device__ __forceinline__ void async16(const void* g, void* l) {
    __builtin_amdgcn_global_load_lds(
        (const __attribute__((address_space(1))) void*)g,
        (__attribute__((address_space(3))) void*)l, 16, 0, 0);
}

// ---------------------------------------------------------------------------
// Mega prep kernel (one launch, all independent preprocessing):
//   [0, 2048)     : x cast -> bf16
//   [2048, 2304)  : w1 -> w1t bf16
//   [2304, 2560)  : base+I -> baset bf16
//   [2560, 2688)  : LayerNorm(ada) -> ae_bf
// ---------------------------------------------------------------------------
__device__ __forceinline__ void tcast_tile(
    const float* __restrict__ in, short* __restrict__ out, int K, int N,
    int bx, int by, bool addI, int tid, float (*t)[68])
{
    const int n0 = bx * 64, k0 = by * 64;
    #pragma unroll
    for (int it = 0; it < 4; ++it) {
        const int idx = it * 256 + tid;
        const int r = idx >> 4, c4 = (idx & 15) * 4;
        float4 v = *(const float4*)(in + (size_t)(k0 + r) * N + n0 + c4);
        t[r][c4 + 0] = v.x; t[r][c4 + 1] = v.y;
        t[r][c4 + 2] = v.z; t[r][c4 + 3] = v.w;
    }
    __syncthreads();
    #pragma unroll
    for (int it = 0; it < 4; ++it) {
        const int idx = it * 256 + tid;
        const int rn = idx >> 4, c4 = (idx & 15) * 4;
        float f0 = t[c4 + 0][rn], f1 = t[c4 + 1][rn];
        float f2 = t[c4 + 2][rn], f3 = t[c4 + 3][rn];
        if (addI) {
            const int n = n0 + rn;
            if (k0 + c4 + 0 == n) f0 += 1.f;
            if (k0 + c4 + 1 == n) f1 += 1.f;
            if (k0 + c4 + 2 == n) f2 += 1.f;
            if (k0 + c4 + 3 == n) f3 += 1.f;
        }
        short4 p;
        p.x = f2bf(f0); p.y = f2bf(f1); p.z = f2bf(f2); p.w = f2bf(f3);
        *(short4*)(out + (size_t)(n0 + rn) * K + k0 + c4) = p;
    }
}

__global__ __launch_bounds__(256) void prep_kernel(
    const float* __restrict__ x, const float* __restrict__ w1,
    const float* __restrict__ base, const float* __restrict__ ada,
    const float* __restrict__ lng, const float* __restrict__ lnb,
    short* __restrict__ x_bf, short* __restrict__ w1t,
    short* __restrict__ baset, short* __restrict__ ae_bf)
{
    __shared__ float t[64][68];
    const int bid = blockIdx.x, tid = threadIdx.x;

    if (bid < 2048) {
        const int i0 = bid * 512 + tid;
        float4 v0 = reinterpret_cast<const float4*>(x)[i0];
        float4 v1 = reinterpret_cast<const float4*>(x)[i0 + 256];
        short4 p0, p1;
        p0.x = f2bf(v0.x); p0.y = f2bf(v0.y); p0.z = f2bf(v0.z); p0.w = f2bf(v0.w);
        p1.x = f2bf(v1.x); p1.y = f2bf(v1.y); p1.z = f2bf(v1.z); p1.w = f2bf(v1.w);
        reinterpret_cast<short4*>(x_bf)[i0] = p0;
        reinterpret_cast<short4*>(x_bf)[i0 + 256] = p1;
    } else if (bid < 2304) {
        const int b = bid - 2048;
        tcast_tile(w1, w1t, NADA, NINT, b & 15, b >> 4, false, tid, t);
    } else if (bid < 2560) {
        const int b = bid - 2304;
        tcast_tile(base, baset, DD, DD, b & 15, b >> 4, true, tid, t);
    } else {
        // LayerNorm, one block per sample
        const int b = bid - 2560;
        const float* row = ada + (size_t)b * NADA;
        float sum = 0.f, sumsq = 0.f;
        for (int i = tid; i < NADA; i += 256) {
            float v = row[i];
            sum += v; sumsq += v * v;
        }
        #pragma unroll
        for (int off = 32; off > 0; off >>= 1) {
            sum   += __shfl_down(sum, off);
            sumsq += __shfl_down(sumsq, off);
        }
        float* s1 = &t[0][0];
        float* s2 = &t[1][0];
        const int wid = tid >> 6, lane = tid & 63;
        if (lane == 0) { s1[wid] = sum; s2[wid] = sumsq; }
        __syncthreads();
        if (tid == 0) {
            float a = 0.f, c = 0.f;
            for (int i = 0; i < 4; ++i) { a += s1[i]; c += s2[i]; }
            s1[0] = a; s2[0] = c;
        }
        __syncthreads();
        const float mu  = s1[0] * (1.f / NADA);
        const float var = s2[0] * (1.f / NADA) - mu * mu;
        const float inv = rsqrtf(var + LNEPS);
        for (int i = tid; i < NADA; i += 256) {
            ae_bf[(size_t)b * NADA + i] = f2bf((row[i] - mu) * inv * lng[i] + lnb[i]);
        }
    }
}

// ---------------------------------------------------------------------------
// bf16 MFMA GEMM (pre-transposed bf16 B). A (M,K), Bt (N,K) bf16 row-major.
// EPI==0: partial to C[z][M][N] (split-K)
// EPI==2: C = acc + rank-8 LoRA; tmat = tp chunk-sum, x_b = partials+b2 sum,
//         both staged to LDS in prologue (fp32)
// ---------------------------------------------------------------------------
template <int BM, int BN, int WM, int WN, int EPI>
__global__ __launch_bounds__(256, 2) void mgemm(
    const short* __restrict__ A, const short* __restrict__ Bt,
    float* __restrict__ C, int M, int N, int K, int kLen,
    const float* __restrict__ tp, const float* __restrict__ p3,
    const float* __restrict__ b2)
{
    constexpr int MT = BM / WM / 16;
    constexpr int NT = BN / WN / 16;
    constexpr int LA = BM / 64;
    constexpr int LB = BN / 64;

    __shared__ __align__(16) short As[BM * 32];
    __shared__ __align__(16) short Bs[BN * 32];
    __shared__ float tmS[(EPI == 2) ? BM * 8 : 1];
    __shared__ float xbS[(EPI == 2) ? (BM / 32) * BN * 8 : 1];

    const int bm = blockIdx.y * BM;
    const int bn = blockIdx.x * BN;
    const int kStart = blockIdx.z * kLen;
    const int tid = threadIdx.x;
    const int wave = tid >> 6, lane = tid & 63;
    const int wm0 = (wave / WN) * (BM / WM);
    const int wn0 = (wave % WN) * (BN / WN);
    const int quad = lane >> 4, r16 = lane & 15;

    if constexpr (EPI == 2) {
        // tmS = sum of TKCH chunks of tp for rows [bm, bm+BM)
        float4 a = {0.f, 0.f, 0.f, 0.f};
        #pragma unroll
        for (int ch = 0; ch < TKCH; ++ch) {
            float4 v = *(const float4*)(tp + (size_t)ch * BB * TT * NRANK
                                           + (size_t)bm * 8 + tid * 4);
            a.x += v.x; a.y += v.y; a.z += v.z; a.w += v.w;
        }
        *(float4*)&tmS[tid * 4] = a;
        // xbS = x_b slice = p3[0] + p3[1] + b2 (x_b half starts at col 8192)
        const int b0 = bm >> 5;
        const int grp = tid >> 6;
        const int inner = tid & 63;
        const size_t off = (size_t)(b0 + grp) * XWN + DD * NRANK + (size_t)bn * 8
                         + inner * 8;
        const int bcol = DD * NRANK + bn * 8 + inner * 8;
        float4 s0a = *(const float4*)(p3 + off);
        float4 s0b = *(const float4*)(p3 + off + 4);
        float4 s1a = *(const float4*)(p3 + (size_t)BB * XWN + off);
        float4 s1b = *(const float4*)(p3 + (size_t)BB * XWN + off + 4);
        float4 ba  = *(const float4*)(b2 + bcol);
        float4 bb  = *(const float4*)(b2 + bcol + 4);
        float4 r0 = {s0a.x + s1a.x + ba.x, s0a.y + s1a.y + ba.y,
                     s0a.z + s1a.z + ba.z, s0a.w + s1a.w + ba.w};
        float4 r1 = {s0b.x + s1b.x + bb.x, s0b.y + s1b.y + bb.y,
                     s0b.z + s1b.z + bb.z, s0b.w + s1b.w + bb.w};
        *(float4*)&xbS[grp * BN * 8 + inner * 8]     = r0;
        *(float4*)&xbS[grp * BN * 8 + inner * 8 + 4] = r1;
    }

    f32x4 acc[MT][NT] = {};

    for (int kt = 0; kt < kLen; kt += 32) {
        const int k0 = kStart + kt;
        #pragma unroll
        for (int s = 0; s < LA; ++s) {
            const int c = s * 256 + tid;
            async16(A + (size_t)(bm + (c >> 2)) * K + k0 + (c & 3) * 8, &As[c * 8]);
        }
        #pragma unroll
        for (int s = 0; s < LB; ++s) {
            const int c = s * 256 + tid;
            async16(Bt + (size_t)(bn + (c >> 2)) * K + k0 + (c & 3) * 8, &Bs[c * 8]);
        }
        __syncthreads();
        bf16x8 af[MT], bfr[NT];
        #pragma unroll
        for (int i = 0; i < MT; ++i)
            af[i] = *reinterpret_cast<const bf16x8*>(&As[(wm0 + i * 16 + r16) * 32 + quad * 8]);
        #pragma unroll
        for (int j = 0; j < NT; ++j)
            bfr[j] = *reinterpret_cast<const bf16x8*>(&Bs[(wn0 + j * 16 + r16) * 32 + quad * 8]);
        #pragma unroll
        for (int i = 0; i < MT; ++i)
            #pragma unroll
            for (int j = 0; j < NT; ++j)
                acc[i][j] = __builtin_amdgcn_mfma_f32_16x16x32_bf16(
                    af[i], bfr[j], acc[i][j], 0, 0, 0);
        __syncthreads();
    }

    // D layout: col = lane&15, row = quad*4 + reg
    if constexpr (EPI == 2) {
        float xbr[NT][8];
        #pragma unroll
        for (int i = 0; i < MT; ++i) {
            const int mlBase = wm0 + i * 16 + quad * 4;
            const int s = mlBase >> 5;
            #pragma unroll
            for (int j = 0; j < NT; ++j) {
                const int nl = wn0 + j * 16 + r16;
                #pragma unroll
                for (int rr = 0; rr < 8; ++rr)
                    xbr[j][rr] = xbS[(s * BN + nl) * 8 + rr];
            }
            #pragma unroll
            for (int r = 0; r < 4; ++r) {
                const int ml = mlBase + r;
                const int m = bm + ml;
                float t8[8];
                #pragma unroll
                for (int rr = 0; rr < 8; ++rr) t8[rr] = tmS[ml * 8 + rr];
                #pragma unroll
                for (int j = 0; j < NT; ++j) {
                    const int n = bn + wn0 + j * 16 + r16;
                    float v = acc[i][j][r];
                    #pragma unroll
                    for (int rr = 0; rr < 8; ++rr) v += t8[rr] * xbr[j][rr];
                    C[(size_t)m * N + n] = v;
                }
            }
        }
    } else {
        #pragma unroll
        for (int i = 0; i < MT; ++i) {
            #pragma unroll
            for (int r = 0; r < 4; ++r) {
                const int m = bm + wm0 + i * 16 + quad * 4 + r;
                #pragma unroll
                for (int j = 0; j < NT; ++j) {
                    const int n = bn + wn0 + j * 16 + r16;
                    C[((size_t)blockIdx.z * M + m) * N + n] = acc[i][j][r];
                }
            }
        }
    }
}

// ---------------------------------------------------------------------------
// gemm3: p3[z] = h_bf @ w2 (z-th K-half). w2 read NATIVE (K,N) fp32;
// transpose+cast read-side in LDS. Plain partial stores (no atomics).
// ---------------------------------------------------------------------------
template <int SPLITK>
__global__ __launch_bounds__(256, 2) void gemm_w2(
    const short* __restrict__ A, const float* __restrict__ W,
    float* __restrict__ P, int M, int N, int K)
{
    constexpr int BM = 128, BN = 64;
    constexpr int MT = 4, NT = 2;
    __shared__ __align__(16) short As[BM * 32];   // 8 KB bf16 [m][k]
    __shared__ __align__(16) float Bf[32 * BN];   // 8 KB fp32 [k][n] (native)

    const int bn = blockIdx.x * BN;
    const int kLen = K / SPLITK;
    const int kStart = blockIdx.z * kLen;
    const int tid = threadIdx.x;
    const int wave = tid >> 6, lane = tid & 63;
    const int wm0 = (wave >> 1) * 64;
    const int wn0 = (wave & 1) * 32;
    const int quad = lane >> 4, r16 = lane & 15;

    f32x4 acc[MT][NT] = {};

    for (int kt = 0; kt < kLen; kt += 32) {
        const int k0 = kStart + kt;
        #pragma unroll
        for (int s = 0; s < 2; ++s) {   // A: 128x32 bf16
            const int c = s * 256 + tid;
            async16(A + (size_t)(c >> 2) * K + k0 + (c & 3) * 8, &As[c * 8]);
        }
        #pragma unroll
        for (int s = 0; s < 2; ++s) {   // B: 32x64 fp32, native layout
            const int c = s * 256 + tid;
            async16(W + (size_t)(k0 + (c >> 4)) * N + bn + (c & 15) * 4, &Bf[c * 4]);
        }
        __syncthreads();
        bf16x8 af[MT], bfr[NT];
        #pragma unroll
        for (int i = 0; i < MT; ++i)
            af[i] = *reinterpret_cast<const bf16x8*>(&As[(wm0 + i * 16 + r16) * 32 + quad * 8]);
        #pragma unroll
        for (int j = 0; j < NT; ++j) {
            const int n = wn0 + j * 16 + r16;
            short tmp[8];
            #pragma unroll
            for (int t = 0; t < 8; ++t)
                tmp[t] = f2bf(Bf[(quad * 8 + t) * BN + n]);   // read-side transpose
            bfr[j] = *reinterpret_cast<const bf16x8*>(tmp);
        }
        #pragma unroll
        for (int i = 0; i < MT; ++i)
            #pragma unroll
            for (int j = 0; j < NT; ++j)
                acc[i][j] = __builtin_amdgcn_mfma_f32_16x16x32_bf16(
                    af[i], bfr[j], acc[i][j], 0, 0, 0);
        __syncthreads();
    }

    #pragma unroll
    for (int i = 0; i < MT; ++i) {
        #pragma unroll
        for (int r = 0; r < 4; ++r) {
            const int m = wm0 + i * 16 + quad * 4 + r;
            #pragma unroll
            for (int j = 0; j < NT; ++j) {
                const int n = bn + wn0 + j * 16 + r16;
                P[((size_t)blockIdx.z * M + m) * N + n] = acc[i][j][r];
            }
        }
    }
}

// ---------------------------------------------------------------------------
// Combine gemm2 split-K partials + bias + exact GELU -> h (bf16)
// ---------------------------------------------------------------------------
__global__ __launch_bounds__(256) void combine_gelu(
    const float* __restrict__ part, const float* __restrict__ b1,
    short* __restrict__ h)
{
    const int idx = blockIdx.x * 256 + threadIdx.x;  // < 128*1024
    float s = b1[idx & (NINT - 1)];
    #pragma unroll
    for (int z = 0; z < SPL2; ++z) s += part[(size_t)z * BB * NINT + idx];
    s = 0.5f * s * (1.f + erff(s * 0.70710678118654752f));
    h[idx] = f2bf(s);
}

// ---------------------------------------------------------------------------
// tmat partials: tp[ch][b][m][r] = sum_{c in chunk} x[b,m,c] * x_a[b,c,r]
// x_a chunk staged as sum of gemm3 partials + b2.
// ---------------------------------------------------------------------------
__global__ __launch_bounds__(256) void tpart_kernel(
    const float* __restrict__ x, const float* __restrict__ p3,
    const float* __restrict__ b2, float* __restrict__ tp)
{
    __shared__ float xa[(DD / TKCH) * NRANK];   // 4 KB chunk [c][r]
    const int b = blockIdx.x, ch = blockIdx.y;
    const int col0 = ch * (DD / TKCH) * NRANK;  // x_a half: cols [0, 8192)
    const size_t off = (size_t)b * XWN + col0;
    {
        const int i4 = threadIdx.x * 4;
        float4 v0 = *(const float4*)(p3 + off + i4);
        float4 v1 = *(const float4*)(p3 + (size_t)BB * XWN + off + i4);
        float4 vb = *(const float4*)(b2 + col0 + i4);
        float4 r = {v0.x + v1.x + vb.x, v0.y + v1.y + vb.y,
                    v0.z + v1.z + vb.z, v0.w + v1.w + vb.w};
        *(float4*)(xa + i4) = r;
    }
    __syncthreads();
    const int m = threadIdx.x >> 3;
    const int r = threadIdx.x & 7;
    const float* xrow = x + ((size_t)b * TT + m) * DD + ch * (DD / TKCH);
    float accv = 0.f;
    #pragma unroll 4
    for (int c = 0; c < DD / TKCH; c += 4) {
        float4 xr = *(const float4*)(xrow + c);
        accv += xr.x * xa[(c + 0) * NRANK + r];
        accv += xr.y * xa[(c + 1) * NRANK + r];
        accv += xr.z * xa[(c + 2) * NRANK + r];
        accv += xr.w * xa[(c + 3) * NRANK + r];
    }
    tp[((size_t)ch * BB * TT + (size_t)b * TT + m) * NRANK + r] = accv;
}

// ---------------------------------------------------------------------------
extern "C" void kernel_launch(void* const* d_in, const int* in_sizes, int n_in,
                              void* d_out, int out_size, void* d_ws, size_t ws_size,
                              hipStream_t stream)
{
    const float* x    = (const float*)d_in[0];
    const float* ada  = (const float*)d_in[1];
    const float* base = (const float*)d_in[2];
    const float* w1   = (const float*)d_in[3];
    const float* b1   = (const float*)d_in[4];
    const float* w2   = (const float*)d_in[5];
    const float* b2   = (const float*)d_in[6];
    const float* lng  = (const float*)d_in[7];
    const float* lnb  = (const float*)d_in[8];
    float* out = (float*)d_out;

    char* w = (char*)d_ws;
    short* x_bf  = (short*)w;  w += (size_t)8 << 20;   // 4096x1024 bf16
    short* w1t   = (short*)w;  w += (size_t)2 << 20;   // 1024x1024 bf16
    short* baset = (short*)w;  w += (size_t)2 << 20;   // 1024x1024 bf16 (base^T + I)
    short* ae_bf = (short*)w;  w += (size_t)256 << 10; // 128x1024 bf16
    short* h_bf  = (short*)w;  w += (size_t)256 << 10; // 128x1024 bf16
    float* p3    = (float*)w;  w += (size_t)16 << 20;  // 2x128x16384 fp32 partials
    float* tp    = (float*)w;  w += (size_t)1 << 20;   // 8x128x32x8 fp32
    float* part  = (float*)w;                          // 4x128x1024 fp32 (2 MB)

    // 1. all preprocessing in one launch (2688 blocks)
    prep_kernel<<<2688, 256, 0, stream>>>(
        x, w1, base, ada, lng, lnb, x_bf, w1t, baset, ae_bf);
    // 2. ae@w1 split-K partials (128 blocks), then gelu+bias -> h_bf
    mgemm<64, 64, 2, 2, 0><<<dim3(NINT / 64, BB / 64, SPL2), 256, 0, stream>>>(
        ae_bf, w1t, part, BB, NINT, NADA, NADA / SPL2, nullptr, nullptr, nullptr);
    combine_gelu<<<BB * NINT / 256, 256, 0, stream>>>(part, b1, h_bf);
    // 3. p3[z] = h@w2 K-half partials (native-layout w2; 256x2 = 512 blocks)
    gemm_w2<SPLW><<<dim3(XWN / 64, 1, SPLW), 256, 0, stream>>>(
        h_bf, w2, p3, BB, XWN, NINT);
    // 4. tmat split-K partials; x_a = p3 sum + b2 (1024 blocks)
    tpart_kernel<<<dim3(BB, TKCH), 256, 0, stream>>>(x, p3, b2, tp);
    // 5. out = x@(base+I) + t@x_b^T; x_b = p3 sum + b2 (512 blocks)
    mgemm<128, 64, 2, 2, 2><<<dim3(DD / 64, BB * TT / 128), 256, 0, stream>>>(
        x_bf, baset, out, BB * TT, DD, DD, DD, tp, p3, b2);
}